// Round 1
// baseline (519.555 us; speedup 1.0000x reference)
//
#include <hip/hip_runtime.h>
#include <cstdint>
#include <cstddef>

// Problem constants (match reference)
#define BB   64
#define TB   2000
#define KB   256
#define NCHK 500          // TB/4 lse-rows chunks per batch

constexpr float LOG2E = 1.4426950408889634f;
constexpr float LN2f  = 0.6931471805599453f;
constexpr float WBF   = 0.36787944117144233f;   // exp(-1) = blank weight (hat domain)

__device__ __forceinline__ float wmax64(float v) {
#pragma unroll
  for (int m = 32; m >= 1; m >>= 1) v = fmaxf(v, __shfl_xor(v, m, 64));
  return v;
}
__device__ __forceinline__ float wsum64(float v) {
#pragma unroll
  for (int m = 32; m >= 1; m >>= 1) v += __shfl_xor(v, m, 64);
  return v;
}
// half-wave (32-lane => 64-state window) max; xor masks <=16 stay within halves
__device__ __forceinline__ float hmax32(float v) {
#pragma unroll
  for (int m = 16; m >= 1; m >>= 1) v = fmaxf(v, __shfl_xor(v, m, 64));
  return v;
}

// ---------------------------------------------------------------------------
// Kernel A: blocks [0,64): per-batch linear-domain CTC forward scan.
//           blocks >=64 : masked log-sum-exp row partials (4 rows/block).
// ---------------------------------------------------------------------------
__global__ __launch_bounds__(256)
void fsl_main(const float* __restrict__ x, const int* __restrict__ key_lens,
              const int* __restrict__ query_lens, float* __restrict__ partial,
              float* __restrict__ alast, float* __restrict__ aprev) {
  __shared__ float pob[2][4];   // boundary odd states (thread 64w+63 -> wave w+1)
  __shared__ int   Clds[8];     // per-64-state-window exponent
  __shared__ float sred[4];
  __shared__ float res2[2];

  if (blockIdx.x < BB) {
    // ---------------- recurrence ----------------
    const int b    = blockIdx.x;
    const int i    = threadIdx.x;        // owns states 2i, 2i+1 (i==255 also 512)
    const int lane = i & 63;
    const int w    = i >> 6;             // wave 0..3
    const int w2   = i >> 5;             // 64-state window 0..7
    const int wm1  = (w > 0) ? (w - 1) : 0;
    const int kl   = key_lens[b];
    const int qlen = query_lens[b];
    const float* xb = x + (size_t)b * (TB * KB);

    float a = 0.f, bs = 0.f, cs = 0.f;   // p[2i], p[2i+1], p[512](i==255)
    int   Cw = 0;
    float adjf = 1.0f;
    if (i == 0) { a = WBF; bs = exp2f(LOG2E * xb[0]); }
    if (lane == 63 && w < 3) pob[0][w] = bs;
    if (i < 8) Clds[i] = 0;
    __syncthreads();

    const float bias = (i < kl) ? 0.f : -20000.f;  // dead key -> w = exp2(-big) = 0
    int cur = 0;
    int t = 1;

    // 8-deep software pipeline of per-thread emit column x[t][i]
    float x0 = xb[(size_t)1 * KB + i];
    float x1 = xb[(size_t)2 * KB + i];
    float x2 = xb[(size_t)3 * KB + i];
    float x3 = xb[(size_t)4 * KB + i];
    float x4 = xb[(size_t)5 * KB + i];
    float x5 = xb[(size_t)6 * KB + i];
    float x6 = xb[(size_t)7 * KB + i];
    float x7 = xb[(size_t)8 * KB + i];

#define STEP(XU) do {                                                        \
    float sh  = __shfl_up(bs, 1, 64);                                        \
    float lv  = pob[cur][wm1];                                               \
    float pm1 = (lane == 0) ? ((w > 0) ? lv : 0.0f) : sh;                    \
    pm1 *= adjf;                                                             \
    float wk = exp2f(fmaf(XU, LOG2E, bias));                                 \
    float na = (a + pm1) * WBF;                                              \
    float nb = (bs + a + pm1) * wk;                                          \
    float nc = (cs + bs) * WBF;                                              \
    bool live = (t < qlen);                                                  \
    a  = live ? na : a;                                                      \
    bs = live ? nb : bs;                                                     \
    cs = live ? nc : cs;                                                     \
    if (lane == 63 && w < 3) pob[cur ^ 1][w] = bs;                           \
    __syncthreads();                                                         \
    cur ^= 1;                                                                \
    int tpf = min(t + 8, TB - 1);                                            \
    XU = xb[(size_t)tpf * KB + i];                                           \
    ++t;                                                                     \
  } while (0)

#define RESCALE() do {                                                       \
    float m = fmaxf(fmaxf(a, bs), cs);                                       \
    m = hmax32(m);                                                           \
    int e = (int)((__float_as_uint(m) >> 23) & 0xFF) - 127;                  \
    e = (m > 0.0f) ? e : 0;                                                  \
    float sc = __uint_as_float((uint32_t)(127 - e) << 23);                   \
    a *= sc; bs *= sc; cs *= sc; Cw += e;                                    \
    if (lane == 63 && w < 3) pob[cur][w] = bs;                               \
    if ((i & 31) == 0) Clds[w2] = Cw;                                        \
    __syncthreads();                                                         \
    int cl = __shfl_up(Cw, 1, 64);                                           \
    if (lane == 0) cl = (w > 0) ? Clds[w2 - 1] : Cw;                         \
    int d = cl - Cw;                                                         \
    d = max(-126, min(24, d));                                               \
    adjf = ((i & 31) == 0) ? __uint_as_float((uint32_t)(127 + d) << 23)      \
                           : 1.0f;                                           \
  } while (0)

    const int nst = qlen - 1;
    const int nch = (nst + 7) >> 3;
    for (int ch = 0; ch < nch; ++ch) {
      STEP(x0); STEP(x1); STEP(x2); STEP(x3);
      RESCALE();
      STEP(x4); STEP(x5); STEP(x6); STEP(x7);
      RESCALE();
    }
#undef STEP
#undef RESCALE

    // readout: last = 2*kl (even -> thread kl's a, or state 512 = cs of thread 255)
    const float myC = (float)Cw;
    if (kl <= 255) {
      if (i == kl)     res2[0] = log2f(a)  + myC;
      if (i == kl - 1) res2[1] = log2f(bs) + myC;
    } else {
      if (i == 255) { res2[0] = log2f(cs) + myC; res2[1] = log2f(bs) + myC; }
    }
    __syncthreads();
    if (i == 0) { alast[b] = res2[0] * LN2f; aprev[b] = res2[1] * LN2f; }

  } else {
    // ---------------- lse row partials ----------------
    const int idx2  = blockIdx.x - BB;          // [0, BB*NCHK)
    const int b     = idx2 / NCHK;
    const int chunk = idx2 - b * NCHK;
    const int wave  = threadIdx.x >> 6;
    const int lane  = threadIdx.x & 63;
    const int t     = chunk * 4 + wave;
    const int kl    = key_lens[b];
    const int qlen  = query_lens[b];

    const float4 v = *(const float4*)(x + ((size_t)b * TB + t) * KB + lane * 4);
    const int c0 = lane * 4;
    float m = -1.0f;                            // blank logit always valid
    if (c0 + 0 < kl) m = fmaxf(m, v.x);
    if (c0 + 1 < kl) m = fmaxf(m, v.y);
    if (c0 + 2 < kl) m = fmaxf(m, v.z);
    if (c0 + 3 < kl) m = fmaxf(m, v.w);
    m = wmax64(m);
    float s = 0.f;
    if (c0 + 0 < kl) s += exp2f((v.x - m) * LOG2E);
    if (c0 + 1 < kl) s += exp2f((v.y - m) * LOG2E);
    if (c0 + 2 < kl) s += exp2f((v.z - m) * LOG2E);
    if (c0 + 3 < kl) s += exp2f((v.w - m) * LOG2E);
    s = wsum64(s);
    s += exp2f((-1.0f - m) * LOG2E);            // blank term, once
    float lv = fmaf(log2f(s), LN2f, m);
    if (lane == 0) sred[wave] = (t < qlen) ? lv : 0.f;
    __syncthreads();
    if (threadIdx.x == 0)
      partial[idx2] = (sred[0] + sred[1]) + (sred[2] + sred[3]);
  }
}

// ---------------------------------------------------------------------------
// Kernel B: per-batch SumLse + loss  (deterministic strided reduction)
// ---------------------------------------------------------------------------
__global__ __launch_bounds__(256)
void fsl_finish(const float* __restrict__ partial, const int* __restrict__ key_lens,
                const float* __restrict__ alast, const float* __restrict__ aprev,
                float* __restrict__ loss) {
  const int b = blockIdx.x;
  const int tid = threadIdx.x;
  float s = 0.f;
  for (int c = tid; c < NCHK; c += 256) s += partial[b * NCHK + c];
  s = wsum64(s);
  __shared__ float sm[4];
  if ((tid & 63) == 0) sm[tid >> 6] = s;
  __syncthreads();
  if (tid == 0) {
    float SumLse = (sm[0] + sm[1]) + (sm[2] + sm[3]);
    float al = alast[b], ap = aprev[b];
    float mx = fmaxf(al, ap);
    float lae;
    if (mx == -INFINITY) lae = -INFINITY;
    else lae = mx + log1pf(expf(-fabsf(al - ap)));
    float nll = SumLse - lae;                    // -(-inf) -> +inf -> guarded
    int kl = key_lens[b];
    float lv = nll / (float)max(kl, 1);
    if (nll > 5e29f) lv = 0.f;
    loss[b] = lv;
  }
}

// ---------------------------------------------------------------------------
// Kernel C: mean over batches
// ---------------------------------------------------------------------------
__global__ void fsl_mean(const float* __restrict__ loss, float* __restrict__ out) {
  float v = loss[threadIdx.x];
  v = wsum64(v);
  if (threadIdx.x == 0) out[0] = v * (1.0f / 64.0f);
}

extern "C" void kernel_launch(void* const* d_in, const int* in_sizes, int n_in,
                              void* d_out, int out_size, void* d_ws, size_t ws_size,
                              hipStream_t stream) {
  const float* x     = (const float*)d_in[0];
  const int*   klens = (const int*)d_in[1];
  const int*   qlens = (const int*)d_in[2];
  float* out = (float*)d_out;

  float* partial = (float*)d_ws;            // BB*NCHK = 32000 floats
  float* alast   = partial + BB * NCHK;     // 64
  float* aprev   = alast + BB;              // 64
  float* loss    = aprev + BB;              // 64   (total ~128.8 KB)

  fsl_main  <<<BB + BB * NCHK, 256, 0, stream>>>(x, klens, qlens, partial, alast, aprev);
  fsl_finish<<<BB, 256, 0, stream>>>(partial, klens, alast, aprev, loss);
  fsl_mean  <<<1, 64, 0, stream>>>(loss, out);
}

// Round 2
// 273.469 us; speedup vs baseline: 1.8999x; 1.8999x over previous
//
#include <hip/hip_runtime.h>
#include <cstdint>
#include <cstddef>

// Problem constants (match reference)
#define BB   64
#define TB   2000
#define KB   256
#define NCHK 500          // TB/4 lse-rows chunks per batch

constexpr float LOG2E = 1.4426950408889634f;
constexpr float LN2f  = 0.6931471805599453f;
constexpr float WBF   = 0.36787944117144233f;   // exp(-1) = blank weight (hat domain)

__device__ __forceinline__ float exp2i(int k) {  // k in [-126, 127], exact 2^k
  return __uint_as_float((uint32_t)(127 + k) << 23);
}
__device__ __forceinline__ float wmax64(float v) {
#pragma unroll
  for (int m = 32; m >= 1; m >>= 1) v = fmaxf(v, __shfl_xor(v, m, 64));
  return v;
}
__device__ __forceinline__ float wsum64(float v) {
#pragma unroll
  for (int m = 32; m >= 1; m >>= 1) v += __shfl_xor(v, m, 64);
  return v;
}

// ---------------------------------------------------------------------------
// Kernel A: blocks [0,64): per-batch linear-domain CTC forward scan with
//           overlapped (halo) tiling — barrier only every 32 steps.
//           blocks >=64 : masked log-sum-exp row partials (4 rows/block).
//
// Scan layout: 4 waves, 2 state-pairs per lane.
//   wave w covers pairs [64w-64, 64w+64); lane l holds p0=64w-64+2l, p1=p0+1.
//   owned (exact) = lanes >=32 (pairs [64w, 64w+64)); lower 64 pairs = halo.
//   Contamination from the missing bottom inflow rises 1 pair/step, so the
//   owned region stays exact for up to 64 steps; we re-import halos every 32.
// ---------------------------------------------------------------------------
__global__ __launch_bounds__(256)
void fsl_main(const float* __restrict__ x, const int* __restrict__ key_lens,
              const int* __restrict__ query_lens, float* __restrict__ partial,
              float* __restrict__ alast, float* __restrict__ aprev) {
  __shared__ float4 sP4[128];   // pair values (a,b) packed 2 pairs per entry
  __shared__ int    sC[4];      // per-wave exponent
  __shared__ float  res2[2];
  __shared__ float  sred[4];

  if (blockIdx.x < BB) {
    const int b    = blockIdx.x;
    const int tid  = threadIdx.x;
    const int lane = tid & 63;
    const int w    = tid >> 6;
    const int p0   = 64 * w - 64 + 2 * lane;
    const int p1   = p0 + 1;
    const int kl   = key_lens[b];
    const int qlen = query_lens[b];
    const float* xb = x + (size_t)b * (TB * KB);
    const bool isl0 = (lane == 0);
    const int  c0cl = max(0, min(p0, KB - 2));       // clamped even col (float2)

    const float bias0 = (p0 >= 0 && p0 < kl) ? 0.f : -20000.f;
    const float bias1 = (p1 >= 0 && p1 < kl) ? 0.f : -20000.f;

    float a0 = 0.f, b0 = 0.f, a1 = 0.f, b1 = 0.f, s512 = 0.f;
    int Cw = 0;
    if (p0 == 0) { a0 = WBF; b0 = exp2f(LOG2E * xb[0]); }  // init owned+halo copies

    // prime 8-deep emit prefetch (rows 1..8)
    float2 r0 = *(const float2*)(xb + (size_t)1 * KB + c0cl);
    float2 r1 = *(const float2*)(xb + (size_t)2 * KB + c0cl);
    float2 r2 = *(const float2*)(xb + (size_t)3 * KB + c0cl);
    float2 r3 = *(const float2*)(xb + (size_t)4 * KB + c0cl);
    float2 r4 = *(const float2*)(xb + (size_t)5 * KB + c0cl);
    float2 r5 = *(const float2*)(xb + (size_t)6 * KB + c0cl);
    float2 r6 = *(const float2*)(xb + (size_t)7 * KB + c0cl);
    float2 r7 = *(const float2*)(xb + (size_t)8 * KB + c0cl);
    int t = 1;

#define STEP(RJ) do {                                                        \
    float pm1 = __shfl_up(b1, 1, 64);                                        \
    pm1 = isl0 ? 0.0f : pm1;                                                 \
    const float w0k = exp2f(fmaf(RJ.x, LOG2E, bias0));                       \
    const float w1k = exp2f(fmaf(RJ.y, LOG2E, bias1));                       \
    const float t0 = a0 + pm1;                                               \
    const float t1 = a1 + b0;                                                \
    const float nb0 = (b0 + t0) * w0k;                                       \
    const float nb1 = (b1 + t1) * w1k;                                       \
    s512 = (s512 + b1) * WBF;                                                \
    a0 = t0 * WBF; a1 = t1 * WBF; b0 = nb0; b1 = nb1;                        \
    const int tn = min(t + 8, TB - 1);                                       \
    RJ = *(const float2*)(xb + (size_t)tn * KB + c0cl);                      \
    ++t;                                                                     \
  } while (0)

#define STEPG(RJ) do {                                                       \
    float pm1 = __shfl_up(b1, 1, 64);                                        \
    pm1 = isl0 ? 0.0f : pm1;                                                 \
    const float w0k = exp2f(fmaf(RJ.x, LOG2E, bias0));                       \
    const float w1k = exp2f(fmaf(RJ.y, LOG2E, bias1));                       \
    const float t0 = a0 + pm1;                                               \
    const float t1 = a1 + b0;                                                \
    const float nb0 = (b0 + t0) * w0k;                                       \
    const float nb1 = (b1 + t1) * w1k;                                       \
    const float ns  = (s512 + b1) * WBF;                                     \
    const bool lv = (t < qlen);                                              \
    a0 = lv ? t0 * WBF : a0; a1 = lv ? t1 * WBF : a1;                        \
    b0 = lv ? nb0 : b0;      b1 = lv ? nb1 : b1;                             \
    s512 = lv ? ns : s512;                                                   \
    const int tn = min(t + 8, TB - 1);                                       \
    RJ = *(const float2*)(xb + (size_t)tn * KB + c0cl);                      \
    ++t;                                                                     \
  } while (0)

#define GR8  do { STEP(r0);STEP(r1);STEP(r2);STEP(r3);STEP(r4);STEP(r5);STEP(r6);STEP(r7); } while (0)
#define GR8G do { STEPG(r0);STEPG(r1);STEPG(r2);STEPG(r3);STEPG(r4);STEPG(r5);STEPG(r6);STEPG(r7); } while (0)

    // wave-local exact power-of-2 rescale (no barrier)
#define RESCALE() do {                                                       \
    float m = fmaxf(fmaxf(a0, b0), fmaxf(a1, b1));                           \
    m = fmaxf(m, s512);                                                      \
    m = wmax64(m);                                                           \
    int e = (int)((__float_as_uint(m) >> 23) & 0xFF) - 127;                  \
    e = (m > 0.f) ? e : 0;                                                   \
    const float sc = exp2i(-e);                                              \
    a0 *= sc; b0 *= sc; a1 *= sc; b1 *= sc; s512 *= sc; Cw += e;             \
  } while (0)

    // halo re-import + scale unification (2 barriers per 32 steps)
#define SYNC() do {                                                          \
    RESCALE();                                                               \
    if (lane >= 32) sP4[32 * w - 32 + lane] = make_float4(a0, b0, a1, b1);   \
    if (lane == 32) sC[w] = Cw;                                              \
    __syncthreads();                                                         \
    const int Cl = (w > 0) ? sC[w - 1] : Cw;                                 \
    const int d = Cl - Cw;                                                   \
    if (d > 0) {            /* adopt larger left scale: never overflow */    \
      const int dcn = min(d, 252), dh = dcn >> 1;                            \
      const float s1 = exp2i(-dh), s2 = exp2i(-(dcn - dh));                  \
      a0 = a0*s1*s2; b0 = b0*s1*s2; a1 = a1*s1*s2; b1 = b1*s1*s2;            \
      s512 = s512*s1*s2; Cw = Cl;                                            \
    }                                                                        \
    if (w > 0 && lane < 32) {                                                \
      const float4 v = sP4[32 * w - 32 + lane];                              \
      const int dc = max(min(d, 0), -252); const int dh2 = dc >> 1;          \
      const float f1 = exp2i(dh2), f2 = exp2i(dc - dh2);                     \
      a0 = v.x*f1*f2; b0 = v.y*f1*f2; a1 = v.z*f1*f2; b1 = v.w*f1*f2;        \
    }                                                                        \
    __syncthreads();                                                         \
  } while (0)

    const int total = qlen - 1;       // live steps t = 1 .. qlen-1
    const int nfull = total >> 5;
    const int rem   = total & 31;
    for (int c = 0; c < nfull; ++c) {
      GR8; GR8;
      RESCALE();
      GR8; GR8;
      SYNC();
    }
    if (rem) {                        // guarded chunk covers the tail
      GR8G; GR8G;
      RESCALE();
      GR8G; GR8G;
      SYNC();
    }
#undef STEP
#undef STEPG
#undef GR8
#undef GR8G
#undef RESCALE
#undef SYNC

    // readout: a_last = state 2*kl, a_prev = state 2*kl-1 (owned lanes only)
    const float fC = (float)Cw;
    if (lane >= 32) {
      if (p0 == kl)     res2[0] = log2f(a0) + fC;
      if (p1 == kl)     res2[0] = log2f(a1) + fC;
      if (p0 == kl - 1) res2[1] = log2f(b0) + fC;
      if (p1 == kl - 1) res2[1] = log2f(b1) + fC;
    }
    if (w == 3 && lane == 63 && kl == 256) {
      res2[0] = log2f(s512) + fC;
      res2[1] = log2f(b1) + fC;       // pair 255 odd = state 511
    }
    __syncthreads();
    if (tid == 0) { alast[b] = res2[0] * LN2f; aprev[b] = res2[1] * LN2f; }

  } else {
    // ---------------- lse row partials ----------------
    const int idx2  = blockIdx.x - BB;          // [0, BB*NCHK)
    const int b     = idx2 / NCHK;
    const int chunk = idx2 - b * NCHK;
    const int wave  = threadIdx.x >> 6;
    const int lane  = threadIdx.x & 63;
    const int t     = chunk * 4 + wave;
    const int kl    = key_lens[b];
    const int qlen  = query_lens[b];

    const float4 v = *(const float4*)(x + ((size_t)b * TB + t) * KB + lane * 4);
    const int c0 = lane * 4;
    float m = -1.0f;                            // blank logit always valid
    if (c0 + 0 < kl) m = fmaxf(m, v.x);
    if (c0 + 1 < kl) m = fmaxf(m, v.y);
    if (c0 + 2 < kl) m = fmaxf(m, v.z);
    if (c0 + 3 < kl) m = fmaxf(m, v.w);
    m = wmax64(m);
    float s = 0.f;
    if (c0 + 0 < kl) s += exp2f((v.x - m) * LOG2E);
    if (c0 + 1 < kl) s += exp2f((v.y - m) * LOG2E);
    if (c0 + 2 < kl) s += exp2f((v.z - m) * LOG2E);
    if (c0 + 3 < kl) s += exp2f((v.w - m) * LOG2E);
    s = wsum64(s);
    s += exp2f((-1.0f - m) * LOG2E);            // blank term, once
    float lv = fmaf(log2f(s), LN2f, m);
    if (lane == 0) sred[wave] = (t < qlen) ? lv : 0.f;
    __syncthreads();
    if (threadIdx.x == 0)
      partial[idx2] = (sred[0] + sred[1]) + (sred[2] + sred[3]);
  }
}

// ---------------------------------------------------------------------------
// Kernel B: per-batch SumLse + loss  (deterministic strided reduction)
// ---------------------------------------------------------------------------
__global__ __launch_bounds__(256)
void fsl_finish(const float* __restrict__ partial, const int* __restrict__ key_lens,
                const float* __restrict__ alast, const float* __restrict__ aprev,
                float* __restrict__ loss) {
  const int b = blockIdx.x;
  const int tid = threadIdx.x;
  float s = 0.f;
  for (int c = tid; c < NCHK; c += 256) s += partial[b * NCHK + c];
  s = wsum64(s);
  __shared__ float sm[4];
  if ((tid & 63) == 0) sm[tid >> 6] = s;
  __syncthreads();
  if (tid == 0) {
    float SumLse = (sm[0] + sm[1]) + (sm[2] + sm[3]);
    float al = alast[b], ap = aprev[b];
    float mx = fmaxf(al, ap);
    float lae;
    if (mx == -INFINITY) lae = -INFINITY;
    else lae = mx + log1pf(expf(-fabsf(al - ap)));
    float nll = SumLse - lae;
    int kl = key_lens[b];
    float lv = nll / (float)max(kl, 1);
    if (nll > 5e29f) lv = 0.f;
    loss[b] = lv;
  }
}

// ---------------------------------------------------------------------------
// Kernel C: mean over batches
// ---------------------------------------------------------------------------
__global__ void fsl_mean(const float* __restrict__ loss, float* __restrict__ out) {
  float v = loss[threadIdx.x];
  v = wsum64(v);
  if (threadIdx.x == 0) out[0] = v * (1.0f / 64.0f);
}

extern "C" void kernel_launch(void* const* d_in, const int* in_sizes, int n_in,
                              void* d_out, int out_size, void* d_ws, size_t ws_size,
                              hipStream_t stream) {
  const float* x     = (const float*)d_in[0];
  const int*   klens = (const int*)d_in[1];
  const int*   qlens = (const int*)d_in[2];
  float* out = (float*)d_out;

  float* partial = (float*)d_ws;            // BB*NCHK = 32000 floats
  float* alast   = partial + BB * NCHK;     // 64
  float* aprev   = alast + BB;              // 64
  float* loss    = aprev + BB;              // 64

  fsl_main  <<<BB + BB * NCHK, 256, 0, stream>>>(x, klens, qlens, partial, alast, aprev);
  fsl_finish<<<BB, 256, 0, stream>>>(partial, klens, alast, aprev, loss);
  fsl_mean  <<<1, 64, 0, stream>>>(loss, out);
}

// Round 3
// 165.576 us; speedup vs baseline: 3.1379x; 1.6516x over previous
//
#include <hip/hip_runtime.h>
#include <cstdint>
#include <cstddef>

// Problem constants (match reference)
#define BB   64
#define TB   2000
#define KB   256
#define NCHK 500          // TB/4 lse-rows chunks per batch

constexpr float LOG2E = 1.4426950408889634f;
constexpr float LN2f  = 0.6931471805599453f;
constexpr float WBF   = 0.36787944117144233f;   // exp(-1) = blank weight (hat domain)

__device__ __forceinline__ float exp2i(int k) {  // k in [-126, 127], exact 2^k
  return __uint_as_float((uint32_t)(127 + k) << 23);
}
__device__ __forceinline__ float wmax64(float v) {
#pragma unroll
  for (int m = 32; m >= 1; m >>= 1) v = fmaxf(v, __shfl_xor(v, m, 64));
  return v;
}
__device__ __forceinline__ float wsum64(float v) {
#pragma unroll
  for (int m = 32; m >= 1; m >>= 1) v += __shfl_xor(v, m, 64);
  return v;
}

// ---------------------------------------------------------------------------
// Kernel A: blocks [0,64): per-batch linear-domain CTC forward scan with
//           overlapped (halo) tiling — barrier only every 32 steps — and a
//           32-deep register prefetch pipeline for the emit columns.
//           blocks >=64 : masked log-sum-exp row partials (4 rows/block).
//
// Scan layout: 4 waves, 2 state-pairs per lane.
//   wave w covers pairs [64w-64, 64w+64); lane l holds p0=64w-64+2l, p1=p0+1.
//   owned (exact) = lanes >=32; lower 64 pairs = halo. Contamination climbs
//   1 pair/step, so owned stays exact for 64 steps; halos re-imported every 32.
// ---------------------------------------------------------------------------
__global__ __launch_bounds__(256)
void fsl_main(const float* __restrict__ x, const int* __restrict__ key_lens,
              const int* __restrict__ query_lens, float* __restrict__ partial,
              float* __restrict__ alast, float* __restrict__ aprev) {
  __shared__ float4 sP4[128];   // exported owned pair values (a0,b0,a1,b1)
  __shared__ int    sC[4];      // per-wave exponent
  __shared__ float  res2[2];
  __shared__ float  sred[4];

  if (blockIdx.x < BB) {
    const int b    = blockIdx.x;
    const int tid  = threadIdx.x;
    const int lane = tid & 63;
    const int w    = tid >> 6;
    const int p0   = 64 * w - 64 + 2 * lane;
    const int p1   = p0 + 1;
    const int kl   = key_lens[b];
    const int qlen = query_lens[b];
    const float* xb = x + (size_t)b * (TB * KB);
    const char*  xbc = (const char*)xb;
    const bool isl0 = (lane == 0);
    const int  c0cl = max(0, min(p0, KB - 2));       // clamped even col (float2)
    const uint32_t col4 = (uint32_t)(c0cl * 4);

    const float bias0 = (p0 >= 0 && p0 < kl) ? 0.f : -20000.f;
    const float bias1 = (p1 >= 0 && p1 < kl) ? 0.f : -20000.f;

    float a0 = 0.f, b0 = 0.f, a1 = 0.f, b1 = 0.f, s512 = 0.f;
    int Cw = 0;
    if (p0 == 0) { a0 = WBF; b0 = __builtin_amdgcn_exp2f(LOG2E * xb[0]); }

    // prime 32-deep emit prefetch (rows 1..32)
#define LD(j) (*(const float2*)(xbc + ((1u + (j)) * 1024u + col4)))
    float2 r0  = LD(0),  r1  = LD(1),  r2  = LD(2),  r3  = LD(3);
    float2 r4  = LD(4),  r5  = LD(5),  r6  = LD(6),  r7  = LD(7);
    float2 r8  = LD(8),  r9  = LD(9),  r10 = LD(10), r11 = LD(11);
    float2 r12 = LD(12), r13 = LD(13), r14 = LD(14), r15 = LD(15);
    float2 r16 = LD(16), r17 = LD(17), r18 = LD(18), r19 = LD(19);
    float2 r20 = LD(20), r21 = LD(21), r22 = LD(22), r23 = LD(23);
    float2 r24 = LD(24), r25 = LD(25), r26 = LD(26), r27 = LD(27);
    float2 r28 = LD(28), r29 = LD(29), r30 = LD(30), r31 = LD(31);
#undef LD
    uint32_t pvoff = 33u * 1024u + col4;               // next row to prefetch
    const uint32_t vmax = 1999u * 1024u + col4;

#define STEP(RJ) do {                                                        \
    float pm1 = __shfl_up(b1, 1, 64);                                        \
    pm1 = isl0 ? 0.0f : pm1;                                                 \
    const float w0k = __builtin_amdgcn_exp2f(fmaf(RJ.x, LOG2E, bias0));      \
    const float w1k = __builtin_amdgcn_exp2f(fmaf(RJ.y, LOG2E, bias1));      \
    const float t0 = a0 + pm1;                                               \
    const float t1 = a1 + b0;                                                \
    const float nb0 = (b0 + t0) * w0k;                                       \
    const float nb1 = (b1 + t1) * w1k;                                       \
    s512 = (s512 + b1) * WBF;                                                \
    a0 = t0 * WBF; a1 = t1 * WBF; b0 = nb0; b1 = nb1;                        \
    RJ = *(const float2*)(xbc + pvoff);                                      \
    pvoff = min(pvoff + 1024u, vmax);                                        \
  } while (0)

#define STEPG(RJ) do {                                                       \
    float pm1 = __shfl_up(b1, 1, 64);                                        \
    pm1 = isl0 ? 0.0f : pm1;                                                 \
    const float w0k = __builtin_amdgcn_exp2f(fmaf(RJ.x, LOG2E, bias0));      \
    const float w1k = __builtin_amdgcn_exp2f(fmaf(RJ.y, LOG2E, bias1));      \
    const float t0 = a0 + pm1;                                               \
    const float t1 = a1 + b0;                                                \
    const float nb0 = (b0 + t0) * w0k;                                       \
    const float nb1 = (b1 + t1) * w1k;                                       \
    const float ns  = (s512 + b1) * WBF;                                     \
    const bool lv = (t < qlen);                                              \
    a0 = lv ? t0 * WBF : a0; a1 = lv ? t1 * WBF : a1;                        \
    b0 = lv ? nb0 : b0;      b1 = lv ? nb1 : b1;                             \
    s512 = lv ? ns : s512;                                                   \
    RJ = *(const float2*)(xbc + pvoff);                                      \
    pvoff = min(pvoff + 1024u, vmax);                                        \
    ++t;                                                                     \
  } while (0)

#define DO8(S,x1,x2,x3,x4,x5,x6,x7,x8) \
  do { S(x1); S(x2); S(x3); S(x4); S(x5); S(x6); S(x7); S(x8); } while (0)

    // wave-local exact power-of-2 rescale (no barrier)
#define RESCALE() do {                                                       \
    float m = fmaxf(fmaxf(a0, b0), fmaxf(a1, b1));                           \
    m = fmaxf(m, s512);                                                      \
    m = wmax64(m);                                                           \
    int e = (int)((__float_as_uint(m) >> 23) & 0xFF) - 127;                  \
    e = (m > 0.f) ? e : 0;                                                   \
    const float sc = exp2i(-e);                                              \
    a0 *= sc; b0 *= sc; a1 *= sc; b1 *= sc; s512 *= sc; Cw += e;             \
  } while (0)

    // halo re-import + scale unification (2 barriers per 32 steps)
#define SYNC() do {                                                          \
    RESCALE();                                                               \
    if (lane >= 32) sP4[32 * w - 32 + lane] = make_float4(a0, b0, a1, b1);   \
    if (lane == 32) sC[w] = Cw;                                              \
    __syncthreads();                                                         \
    const int Cl = (w > 0) ? sC[w - 1] : Cw;                                 \
    const int d = Cl - Cw;                                                   \
    if (d > 0) {            /* adopt larger left scale: never overflow */    \
      const int dcn = min(d, 252), dh = dcn >> 1;                            \
      const float s1 = exp2i(-dh), s2 = exp2i(-(dcn - dh));                  \
      a0 = a0*s1*s2; b0 = b0*s1*s2; a1 = a1*s1*s2; b1 = b1*s1*s2;            \
      s512 = s512*s1*s2; Cw = Cl;                                            \
    }                                                                        \
    if (w > 0 && lane < 32) {                                                \
      const float4 v = sP4[32 * w - 32 + lane];                              \
      const int dc = max(min(d, 0), -252); const int dh2 = dc >> 1;          \
      const float f1 = exp2i(dh2), f2 = exp2i(dc - dh2);                     \
      a0 = v.x*f1*f2; b0 = v.y*f1*f2; a1 = v.z*f1*f2; b1 = v.w*f1*f2;        \
    }                                                                        \
    __syncthreads();                                                         \
  } while (0)

    const int total = qlen - 1;       // live steps t = 1 .. qlen-1
    const int nfull = total >> 5;
    const int rem   = total & 31;
    for (int c = 0; c < nfull; ++c) {
      DO8(STEP, r0, r1, r2, r3, r4, r5, r6, r7);
      DO8(STEP, r8, r9, r10, r11, r12, r13, r14, r15);
      RESCALE();
      DO8(STEP, r16, r17, r18, r19, r20, r21, r22, r23);
      DO8(STEP, r24, r25, r26, r27, r28, r29, r30, r31);
      SYNC();
    }
    if (rem) {                        // guarded chunk covers the tail
      int t = 1 + (nfull << 5);
      DO8(STEPG, r0, r1, r2, r3, r4, r5, r6, r7);
      DO8(STEPG, r8, r9, r10, r11, r12, r13, r14, r15);
      RESCALE();
      DO8(STEPG, r16, r17, r18, r19, r20, r21, r22, r23);
      DO8(STEPG, r24, r25, r26, r27, r28, r29, r30, r31);
      SYNC();
    }
#undef STEP
#undef STEPG
#undef DO8
#undef RESCALE
#undef SYNC

    // readout: a_last = state 2*kl, a_prev = state 2*kl-1 (owned lanes only)
    const float fC = (float)Cw;
    if (lane >= 32) {
      if (p0 == kl)     res2[0] = log2f(a0) + fC;
      if (p1 == kl)     res2[0] = log2f(a1) + fC;
      if (p0 == kl - 1) res2[1] = log2f(b0) + fC;
      if (p1 == kl - 1) res2[1] = log2f(b1) + fC;
    }
    if (w == 3 && lane == 63 && kl == 256) {
      res2[0] = log2f(s512) + fC;
      res2[1] = log2f(b1) + fC;       // pair 255 odd = state 511
    }
    __syncthreads();
    if (tid == 0) { alast[b] = res2[0] * LN2f; aprev[b] = res2[1] * LN2f; }

  } else {
    // ---------------- lse row partials ----------------
    const int idx2  = blockIdx.x - BB;          // [0, BB*NCHK)
    const int b     = idx2 / NCHK;
    const int chunk = idx2 - b * NCHK;
    const int wave  = threadIdx.x >> 6;
    const int lane  = threadIdx.x & 63;
    const int t     = chunk * 4 + wave;
    const int kl    = key_lens[b];
    const int qlen  = query_lens[b];

    const float4 v = *(const float4*)(x + ((size_t)b * TB + t) * KB + lane * 4);
    const int c0 = lane * 4;
    float m = -1.0f;                            // blank logit always valid
    if (c0 + 0 < kl) m = fmaxf(m, v.x);
    if (c0 + 1 < kl) m = fmaxf(m, v.y);
    if (c0 + 2 < kl) m = fmaxf(m, v.z);
    if (c0 + 3 < kl) m = fmaxf(m, v.w);
    m = wmax64(m);
    float s = 0.f;
    if (c0 + 0 < kl) s += __builtin_amdgcn_exp2f((v.x - m) * LOG2E);
    if (c0 + 1 < kl) s += __builtin_amdgcn_exp2f((v.y - m) * LOG2E);
    if (c0 + 2 < kl) s += __builtin_amdgcn_exp2f((v.z - m) * LOG2E);
    if (c0 + 3 < kl) s += __builtin_amdgcn_exp2f((v.w - m) * LOG2E);
    s = wsum64(s);
    s += __builtin_amdgcn_exp2f((-1.0f - m) * LOG2E);   // blank term, once
    float lv = fmaf(__builtin_amdgcn_logf(s), LN2f, m);
    if (lane == 0) sred[wave] = (t < qlen) ? lv : 0.f;
    __syncthreads();
    if (threadIdx.x == 0)
      partial[idx2] = (sred[0] + sred[1]) + (sred[2] + sred[3]);
  }
}

// ---------------------------------------------------------------------------
// Kernel B: per-batch SumLse + loss + mean, one block.
//   4 threads per batch sum 125 partials each, combine via shfl, then
//   block-reduce the 64 per-batch losses.
// ---------------------------------------------------------------------------
__global__ __launch_bounds__(256)
void fsl_finish(const float* __restrict__ partial, const int* __restrict__ key_lens,
                const float* __restrict__ alast, const float* __restrict__ aprev,
                float* __restrict__ out) {
  const int tid = threadIdx.x;
  const int b = tid >> 2, q = tid & 3;
  float s = 0.f;
  const float* pb = partial + b * NCHK + q * 125;
#pragma unroll 5
  for (int j = 0; j < 125; ++j) s += pb[j];
  s += __shfl_xor(s, 1, 64);
  s += __shfl_xor(s, 2, 64);
  float lossb = 0.f;
  if (q == 0) {
    const float SumLse = s;
    const float al = alast[b], ap = aprev[b];
    const float mx = fmaxf(al, ap);
    const float lae = (mx == -INFINITY) ? -INFINITY
                                        : mx + log1pf(expf(-fabsf(al - ap)));
    const float nll = SumLse - lae;
    const int kl = key_lens[b];
    float lv = nll / (float)max(kl, 1);
    if (nll > 5e29f) lv = 0.f;
    lossb = lv;
  }
  float v = wsum64(lossb);
  __shared__ float sm[4];
  if ((tid & 63) == 0) sm[tid >> 6] = v;
  __syncthreads();
  if (tid == 0) out[0] = ((sm[0] + sm[1]) + (sm[2] + sm[3])) * (1.0f / 64.0f);
}

extern "C" void kernel_launch(void* const* d_in, const int* in_sizes, int n_in,
                              void* d_out, int out_size, void* d_ws, size_t ws_size,
                              hipStream_t stream) {
  const float* x     = (const float*)d_in[0];
  const int*   klens = (const int*)d_in[1];
  const int*   qlens = (const int*)d_in[2];
  float* out = (float*)d_out;

  float* partial = (float*)d_ws;            // BB*NCHK = 32000 floats
  float* alast   = partial + BB * NCHK;     // 64
  float* aprev   = alast + BB;              // 64

  fsl_main  <<<BB + BB * NCHK, 256, 0, stream>>>(x, klens, qlens, partial, alast, aprev);
  fsl_finish<<<1, 256, 0, stream>>>(partial, klens, alast, aprev, out);
}